// Round 2
// baseline (519.988 us; speedup 1.0000x reference)
//
#include <hip/hip_runtime.h>

#define HW 1024
#define WW 32

// ---------------------------------------------------------------------------
// helpers for PPT-wide vector load/store
// ---------------------------------------------------------------------------
template<int PPT> __device__ inline void vload(float* d, const float* s);
template<> __device__ inline void vload<4>(float* d, const float* s) {
    float4 t = *(const float4*)s; d[0] = t.x; d[1] = t.y; d[2] = t.z; d[3] = t.w;
}
template<> __device__ inline void vload<2>(float* d, const float* s) {
    float2 t = *(const float2*)s; d[0] = t.x; d[1] = t.y;
}
template<int PPT> __device__ inline void vstore(float* d, const float* s);
template<> __device__ inline void vstore<4>(float* d, const float* s) {
    *(float4*)d = make_float4(s[0], s[1], s[2], s[3]);
}
template<> __device__ inline void vstore<2>(float* d, const float* s) {
    *(float2*)d = make_float2(s[0], s[1]);
}

// ---------------------------------------------------------------------------
// 1x1 conv + optional concat second input + optional BN + optional ReLU.
// Weights staged in LDS (8 output rows), activations as PPT-wide vectors.
// in1: (B,c1tot,HW) ch [off1,off1+c1);  in2 optional: (B,c2tot,HW) ch [off2..)
// w: (cout, c1+c2) row-major.  out: (B,cout,HW)
// grid: (HW/(256*PPT), cout/8, B), block 256.
// ---------------------------------------------------------------------------
template<int PPT>
__global__ __launch_bounds__(256) void conv1x1_kernel(
    const float* __restrict__ in1, int c1tot, int off1, int c1,
    const float* __restrict__ in2, int c2tot, int off2, int c2,
    const float* __restrict__ w,
    const float* __restrict__ g, const float* __restrict__ bb,
    float* __restrict__ out, int cout, int relu)
{
    __shared__ float wS[8][256];
    const int cin = c1 + c2;
    const int co0 = blockIdx.y * 8;
    const int b   = blockIdx.z;
    const int p0  = blockIdx.x * 256 * PPT + threadIdx.x * PPT;

    // stage 8 weight rows into LDS
    for (int r = 0; r < 8; ++r)
        for (int cc = threadIdx.x; cc < cin; cc += 256)
            wS[r][cc] = w[(size_t)(co0 + r) * cin + cc];
    __syncthreads();

    float acc[8][PPT];
#pragma unroll
    for (int r = 0; r < 8; ++r)
#pragma unroll
        for (int q = 0; q < PPT; ++q) acc[r][q] = 0.f;

    const float* in1b = in1 + ((size_t)b * c1tot + off1) * HW + p0;
    for (int ci = 0; ci < c1; ci += 2) {
        float va[PPT], vb[PPT];
        vload<PPT>(va, in1b + (size_t)ci * HW);
        vload<PPT>(vb, in1b + (size_t)(ci + 1) * HW);
#pragma unroll
        for (int r = 0; r < 8; ++r) {
            float2 wv = *(const float2*)&wS[r][ci];
#pragma unroll
            for (int q = 0; q < PPT; ++q)
                acc[r][q] += wv.x * va[q] + wv.y * vb[q];
        }
    }
    if (in2) {
        const float* in2b = in2 + ((size_t)b * c2tot + off2) * HW + p0;
        for (int ci = 0; ci < c2; ci += 2) {
            float va[PPT], vb[PPT];
            vload<PPT>(va, in2b + (size_t)ci * HW);
            vload<PPT>(vb, in2b + (size_t)(ci + 1) * HW);
#pragma unroll
            for (int r = 0; r < 8; ++r) {
                float2 wv = *(const float2*)&wS[r][c1 + ci];
#pragma unroll
                for (int q = 0; q < PPT; ++q)
                    acc[r][q] += wv.x * va[q] + wv.y * vb[q];
            }
        }
    }

#pragma unroll
    for (int r = 0; r < 8; ++r) {
        const int co = co0 + r;
        const float gg = g ? g[co] : 1.f;
        const float bv = g ? bb[co] : 0.f;
        float o[PPT];
#pragma unroll
        for (int q = 0; q < PPT; ++q) {
            float t = acc[r][q] * gg + bv;
            if (relu) t = fmaxf(t, 0.f);
            o[q] = t;
        }
        vstore<PPT>(out + ((size_t)b * cout + co) * HW + p0, o);
    }
}

// ---------------------------------------------------------------------------
// Attention partial pass (flash-decoding split over j).
// Each block: one (b,h), one 256-query tile, one j-chunk of 512 keys.
// No LDS staging: K/V reads are wave-uniform -> L1/L2 broadcast (qkv is
// L2-resident at 12.6 MB).
// Writes unnormalized acc[16] + (m, l) per query to `part`.
// part layout: [bh][jc][18][1024]
// grid: (4, 2, 64), block 256.
// ---------------------------------------------------------------------------
__global__ __launch_bounds__(256) void attn_part_kernel(
    const float* __restrict__ qkv, float* __restrict__ part)
{
    const int bh = blockIdx.z;           // b*8 + h
    const int jc = blockIdx.y;
    const int i  = blockIdx.x * 256 + threadIdx.x;
    const float scale = 0.25f;           // 16^-0.5

    const float* base = qkv + (size_t)bh * 48 * HW;

    float q[16];
#pragma unroll
    for (int d = 0; d < 16; ++d) q[d] = base[(size_t)d * HW + i] * scale;

    float m = -1e30f, l = 0.f;
    float acc[16];
#pragma unroll
    for (int d = 0; d < 16; ++d) acc[d] = 0.f;

    const int j0 = jc * 512;
    for (int jj = j0; jj < j0 + 512; jj += 4) {
        float4 kv[16];
#pragma unroll
        for (int d = 0; d < 16; ++d)
            kv[d] = *(const float4*)(base + (size_t)(16 + d) * HW + jj);
        float s0 = 0.f, s1 = 0.f, s2 = 0.f, s3 = 0.f;
#pragma unroll
        for (int d = 0; d < 16; ++d) {
            s0 += q[d] * kv[d].x; s1 += q[d] * kv[d].y;
            s2 += q[d] * kv[d].z; s3 += q[d] * kv[d].w;
        }
        const float m4 = fmaxf(fmaxf(s0, s1), fmaxf(s2, s3));
        const float mn = fmaxf(m, m4);
        const float p0 = __expf(s0 - mn), p1 = __expf(s1 - mn);
        const float p2 = __expf(s2 - mn), p3 = __expf(s3 - mn);
        if (mn > m) {
            const float c = __expf(m - mn);
            l *= c;
#pragma unroll
            for (int d = 0; d < 16; ++d) acc[d] *= c;
            m = mn;
        }
        l += (p0 + p1) + (p2 + p3);
#pragma unroll
        for (int d = 0; d < 16; ++d) {
            float4 vv = *(const float4*)(base + (size_t)(32 + d) * HW + jj);
            acc[d] += p0 * vv.x + p1 * vv.y + p2 * vv.z + p3 * vv.w;
        }
    }

    float* pp = part + ((size_t)(bh * 2 + jc) * 18) * 1024 + i;
#pragma unroll
    for (int d = 0; d < 16; ++d) pp[(size_t)d * 1024] = acc[d];
    pp[16 * 1024] = m;
    pp[17 * 1024] = l;
}

// ---------------------------------------------------------------------------
// Merge the 2 j-chunk partials, normalize, add depthwise-3x3 PE of v.
// grid: (4, 8, 8), block 256.  att: (B,128,HW)
// ---------------------------------------------------------------------------
__global__ __launch_bounds__(256) void attn_merge_kernel(
    const float* __restrict__ part, const float* __restrict__ qkv,
    const float* __restrict__ pe_w, float* __restrict__ att)
{
    const int i = blockIdx.x * 256 + threadIdx.x;
    const int h = blockIdx.y, b = blockIdx.z;
    const int bh = b * 8 + h;

    const float* p0 = part + ((size_t)(bh * 2 + 0) * 18) * 1024 + i;
    const float* p1 = part + ((size_t)(bh * 2 + 1) * 18) * 1024 + i;
    const float m0 = p0[16 * 1024], l0 = p0[17 * 1024];
    const float m1 = p1[16 * 1024], l1 = p1[17 * 1024];
    const float M  = fmaxf(m0, m1);
    const float s0 = __expf(m0 - M), s1 = __expf(m1 - M);
    const float inv = 1.f / (l0 * s0 + l1 * s1);

    const float* vbase = qkv + ((size_t)bh * 48 + 32) * HW;
    const int y = i >> 5, x = i & 31;

#pragma unroll
    for (int d = 0; d < 16; ++d) {
        float o = (p0[(size_t)d * 1024] * s0 + p1[(size_t)d * 1024] * s1) * inv;
        const float* vm = vbase + (size_t)d * HW;
        const float* wk = pe_w + (size_t)(h * 16 + d) * 9;
        float s = 0.f;
#pragma unroll
        for (int ky = 0; ky < 3; ++ky) {
            const int yy = y + ky - 1;
            if (yy < 0 || yy > 31) continue;
#pragma unroll
            for (int kx = 0; kx < 3; ++kx) {
                const int xx = x + kx - 1;
                if (xx < 0 || xx > 31) continue;
                s += wk[ky * 3 + kx] * vm[yy * WW + xx];
            }
        }
        att[((size_t)b * 128 + h * 16 + d) * HW + i] = o + s;
    }
}

// ---------------------------------------------------------------------------
extern "C" void kernel_launch(void* const* d_in, const int* in_sizes, int n_in,
                              void* d_out, int out_size, void* d_ws, size_t ws_size,
                              hipStream_t stream)
{
    const float* x      = (const float*)d_in[0];
    const float* cv1_w  = (const float*)d_in[1];
    const float* bn1_g  = (const float*)d_in[2];
    const float* bn1_b  = (const float*)d_in[3];
    const float* qkv_w  = (const float*)d_in[4];
    const float* pe_w   = (const float*)d_in[5];
    const float* proj_w = (const float*)d_in[6];
    const float* ffn1_w = (const float*)d_in[7];
    const float* fbn1_g = (const float*)d_in[8];
    const float* fbn1_b = (const float*)d_in[9];
    const float* ffn2_w = (const float*)d_in[10];
    const float* fbn2_g = (const float*)d_in[11];
    const float* fbn2_b = (const float*)d_in[12];
    const float* cv2_w  = (const float*)d_in[13];
    const float* bn2_g  = (const float*)d_in[14];
    const float* bn2_b  = (const float*)d_in[15];
    float* out = (float*)d_out;

    const int B = 8;
    float* ws = (float*)d_ws;
    // workspace plan (float offsets):
    //   y    @ 0          2,097,152   (cv1 out; b_branch lives until cv2)
    //   qkv  @ 2,097,152  3,145,728   (dead after merge)
    //   part @ 5,242,880  2,359,296   (64*2*18*1024; dead after merge)
    //   att  @ 7,602,176  1,048,576   (dead after proj)
    //   a2   @ 5,242,880  1,048,576   (reuse part; proj out)
    //   f1   @ 6,291,456  2,097,152   (reuse part+att tail; after proj)
    //   f2   @ 8,650,752  1,048,576
    // peak = 9,699,328 floats = 38.8 MB
    float* y    = ws;
    float* qkv  = ws + 2097152;
    float* part = ws + 5242880;
    float* att  = ws + 7602176;
    float* a2   = ws + 5242880;
    float* f1   = ws + 6291456;
    float* f2   = ws + 8650752;

    dim3 blk(256);

    // 1) cv1: x(256) -> y(256), BN+ReLU
    conv1x1_kernel<4><<<dim3(1, 32, B), blk, 0, stream>>>(
        x, 256, 0, 256, nullptr, 0, 0, 0, cv1_w, bn1_g, bn1_b, y, 256, 1);

    // 2) qkv: a = y[:,0:128] -> qkv(384)
    conv1x1_kernel<4><<<dim3(1, 48, B), blk, 0, stream>>>(
        y, 256, 0, 128, nullptr, 0, 0, 0, qkv_w, nullptr, nullptr, qkv, 384, 0);

    // 3) attention partials (split-j x2)
    attn_part_kernel<<<dim3(4, 2, 64), blk, 0, stream>>>(qkv, part);

    // 4) merge + PE depthwise 3x3 -> att(128)
    attn_merge_kernel<<<dim3(4, 8, B), blk, 0, stream>>>(part, qkv, pe_w, att);

    // 5) proj: att(128) -> a2(128)
    conv1x1_kernel<2><<<dim3(2, 16, B), blk, 0, stream>>>(
        att, 128, 0, 128, nullptr, 0, 0, 0, proj_w, nullptr, nullptr, a2, 128, 0);

    // 6) ffn1: a2(128) -> f1(256), BN+ReLU
    conv1x1_kernel<4><<<dim3(1, 32, B), blk, 0, stream>>>(
        a2, 128, 0, 128, nullptr, 0, 0, 0, ffn1_w, fbn1_g, fbn1_b, f1, 256, 1);

    // 7) ffn2: f1(256) -> f2(128), BN (no ReLU)
    conv1x1_kernel<2><<<dim3(2, 16, B), blk, 0, stream>>>(
        f1, 256, 0, 256, nullptr, 0, 0, 0, ffn2_w, fbn2_g, fbn2_b, f2, 128, 0);

    // 8) cv2: concat(f2(128), y[:,128:256]) -> out(256), BN+ReLU
    conv1x1_kernel<4><<<dim3(1, 32, B), blk, 0, stream>>>(
        f2, 128, 0, 128, y, 256, 128, 128, cv2_w, bn2_g, bn2_b, out, 256, 1);
}

// Round 5
// 427.009 us; speedup vs baseline: 1.2177x; 1.2177x over previous
//
#include <hip/hip_runtime.h>

#define HW 1024
#define WW 32

// ---------------------------------------------------------------------------
// 1x1 conv (+optional concat input 2) + optional BN + optional ReLU.
// Compile-time input channel counts so the K-loop fully unrolls/pipelines.
// Weights are read with block-uniform indices -> scalar loads (SGPR operands).
// thread = 8 output channels x 2 pixels. grid: (2, cout/8, B), block 256.
// ---------------------------------------------------------------------------
template<int C1, int C2>
__global__ __launch_bounds__(256) void conv1x1_kernel(
    const float* __restrict__ in1, int c1tot, int off1,
    const float* __restrict__ in2, int c2tot, int off2,
    const float* __restrict__ w,
    const float* __restrict__ g, const float* __restrict__ bb,
    float* __restrict__ out, int cout, int relu)
{
    constexpr int CIN = C1 + C2;
    const int co0 = blockIdx.y * 8;
    const int b   = blockIdx.z;
    const int p0  = blockIdx.x * 512 + threadIdx.x * 2;

    float acc[8][2];
#pragma unroll
    for (int r = 0; r < 8; ++r) { acc[r][0] = 0.f; acc[r][1] = 0.f; }

    const float* in1b = in1 + ((size_t)b * c1tot + off1) * HW + p0;
#pragma unroll 2
    for (int ci = 0; ci < C1; ci += 8) {
        float2 a[8];
#pragma unroll
        for (int u = 0; u < 8; ++u)
            a[u] = *(const float2*)(in1b + (size_t)(ci + u) * HW);
#pragma unroll
        for (int r = 0; r < 8; ++r) {
            const float* wr = w + (size_t)(co0 + r) * CIN + ci;
            float4 w0 = *(const float4*)wr;
            float4 w1 = *(const float4*)(wr + 4);
            acc[r][0] += w0.x * a[0].x + w0.y * a[1].x + w0.z * a[2].x + w0.w * a[3].x
                       + w1.x * a[4].x + w1.y * a[5].x + w1.z * a[6].x + w1.w * a[7].x;
            acc[r][1] += w0.x * a[0].y + w0.y * a[1].y + w0.z * a[2].y + w0.w * a[3].y
                       + w1.x * a[4].y + w1.y * a[5].y + w1.z * a[6].y + w1.w * a[7].y;
        }
    }
    if constexpr (C2 > 0) {
        const float* in2b = in2 + ((size_t)b * c2tot + off2) * HW + p0;
#pragma unroll 2
        for (int ci = 0; ci < C2; ci += 8) {
            float2 a[8];
#pragma unroll
            for (int u = 0; u < 8; ++u)
                a[u] = *(const float2*)(in2b + (size_t)(ci + u) * HW);
#pragma unroll
            for (int r = 0; r < 8; ++r) {
                const float* wr = w + (size_t)(co0 + r) * CIN + C1 + ci;
                float4 w0 = *(const float4*)wr;
                float4 w1 = *(const float4*)(wr + 4);
                acc[r][0] += w0.x * a[0].x + w0.y * a[1].x + w0.z * a[2].x + w0.w * a[3].x
                           + w1.x * a[4].x + w1.y * a[5].x + w1.z * a[6].x + w1.w * a[7].x;
                acc[r][1] += w0.x * a[0].y + w0.y * a[1].y + w0.z * a[2].y + w0.w * a[3].y
                           + w1.x * a[4].y + w1.y * a[5].y + w1.z * a[6].y + w1.w * a[7].y;
            }
        }
    }

#pragma unroll
    for (int r = 0; r < 8; ++r) {
        const int co = co0 + r;
        float t0 = acc[r][0], t1 = acc[r][1];
        if (g) {
            const float gg = g[co], bv = bb[co];
            t0 = t0 * gg + bv; t1 = t1 * gg + bv;
        }
        if (relu) { t0 = fmaxf(t0, 0.f); t1 = fmaxf(t1, 0.f); }
        *(float2*)(out + ((size_t)b * cout + co) * HW + p0) = make_float2(t0, t1);
    }
}

// ---------------------------------------------------------------------------
// Attention partials: flash-decoding split over j (fixed Jc=2).
// 2 queries per thread. grid: (2, 2, 64), block 256. thread t of x-block xb
// handles queries i0 = xb*512+t and i1 = i0+256 (coalesced).
// part layout: [bh][jc][18][1024] (16 acc rows + m + l).
// ---------------------------------------------------------------------------
__global__ __launch_bounds__(256) void attn_part_kernel(
    const float* __restrict__ qkv, float* __restrict__ part, int jlen)
{
    const int bh = blockIdx.z;
    const int jc = blockIdx.y;
    const int i0 = blockIdx.x * 512 + threadIdx.x;
    const int i1 = i0 + 256;
    const float scale = 0.25f;

    const float* base = qkv + (size_t)bh * 48 * HW;

    float q0[16], q1[16];
#pragma unroll
    for (int d = 0; d < 16; ++d) {
        q0[d] = base[(size_t)d * HW + i0] * scale;
        q1[d] = base[(size_t)d * HW + i1] * scale;
    }

    float m0 = -1e30f, l0 = 0.f, m1 = -1e30f, l1 = 0.f;
    float acc0[16], acc1[16];
#pragma unroll
    for (int d = 0; d < 16; ++d) { acc0[d] = 0.f; acc1[d] = 0.f; }

    const int j0 = jc * jlen;
    for (int jj = j0; jj < j0 + jlen; jj += 4) {
        float4 kf[16];
#pragma unroll
        for (int d = 0; d < 16; ++d)
            kf[d] = *(const float4*)(base + (size_t)(16 + d) * HW + jj);

        float s00 = 0.f, s01 = 0.f, s02 = 0.f, s03 = 0.f;
        float s10 = 0.f, s11 = 0.f, s12 = 0.f, s13 = 0.f;
#pragma unroll
        for (int d = 0; d < 16; ++d) {
            s00 += q0[d] * kf[d].x; s01 += q0[d] * kf[d].y;
            s02 += q0[d] * kf[d].z; s03 += q0[d] * kf[d].w;
            s10 += q1[d] * kf[d].x; s11 += q1[d] * kf[d].y;
            s12 += q1[d] * kf[d].z; s13 += q1[d] * kf[d].w;
        }

        // issue V loads before the softmax math so latency hides under exp
        float4 vf[16];
#pragma unroll
        for (int d = 0; d < 16; ++d)
            vf[d] = *(const float4*)(base + (size_t)(32 + d) * HW + jj);

        // q0 softmax update
        float m4 = fmaxf(fmaxf(s00, s01), fmaxf(s02, s03));
        float mn = fmaxf(m0, m4);
        float p0 = __expf(s00 - mn), p1 = __expf(s01 - mn);
        float p2 = __expf(s02 - mn), p3 = __expf(s03 - mn);
        if (mn > m0) {
            const float c = __expf(m0 - mn);
            l0 *= c;
#pragma unroll
            for (int d = 0; d < 16; ++d) acc0[d] *= c;
            m0 = mn;
        }
        l0 += (p0 + p1) + (p2 + p3);
        // q1 softmax update
        float n4 = fmaxf(fmaxf(s10, s11), fmaxf(s12, s13));
        float nn = fmaxf(m1, n4);
        float r0 = __expf(s10 - nn), r1 = __expf(s11 - nn);
        float r2 = __expf(s12 - nn), r3 = __expf(s13 - nn);
        if (nn > m1) {
            const float c = __expf(m1 - nn);
            l1 *= c;
#pragma unroll
            for (int d = 0; d < 16; ++d) acc1[d] *= c;
            m1 = nn;
        }
        l1 += (r0 + r1) + (r2 + r3);

#pragma unroll
        for (int d = 0; d < 16; ++d) {
            acc0[d] += p0 * vf[d].x + p1 * vf[d].y + p2 * vf[d].z + p3 * vf[d].w;
            acc1[d] += r0 * vf[d].x + r1 * vf[d].y + r2 * vf[d].z + r3 * vf[d].w;
        }
    }

    float* pp = part + ((size_t)bh * 2 + jc) * 18 * 1024;
#pragma unroll
    for (int d = 0; d < 16; ++d) {
        pp[(size_t)d * 1024 + i0] = acc0[d];
        pp[(size_t)d * 1024 + i1] = acc1[d];
    }
    pp[16 * 1024 + i0] = m0; pp[17 * 1024 + i0] = l0;
    pp[16 * 1024 + i1] = m1; pp[17 * 1024 + i1] = l1;
}

// ---------------------------------------------------------------------------
// Merge the 2 j-chunk partials, normalize, add depthwise-3x3 PE of v.
// grid: (4, 8, 8), block 256.
// ---------------------------------------------------------------------------
__global__ __launch_bounds__(256) void attn_merge_kernel(
    const float* __restrict__ part, const float* __restrict__ qkv,
    const float* __restrict__ pe_w, float* __restrict__ att)
{
    const int i = blockIdx.x * 256 + threadIdx.x;
    const int h = blockIdx.y, b = blockIdx.z;
    const int bh = b * 8 + h;

    const float* pb = part + (size_t)bh * 2 * 18 * 1024 + i;
    const float m0 = pb[(size_t)16 * 1024],        l0 = pb[(size_t)17 * 1024];
    const float m1 = pb[(size_t)(18 + 16) * 1024], l1 = pb[(size_t)(18 + 17) * 1024];
    const float M  = fmaxf(m0, m1);
    const float s0 = __expf(m0 - M), s1 = __expf(m1 - M);
    const float inv = 1.f / (l0 * s0 + l1 * s1);

    const float* vbase = qkv + ((size_t)bh * 48 + 32) * HW;
    const int y = i >> 5, x = i & 31;

#pragma unroll
    for (int d = 0; d < 16; ++d) {
        float o = (pb[(size_t)d * 1024] * s0 + pb[(size_t)(18 + d) * 1024] * s1) * inv;
        const float* vm = vbase + (size_t)d * HW;
        const float* wk = pe_w + (size_t)(h * 16 + d) * 9;
        float pe = 0.f;
#pragma unroll
        for (int ky = 0; ky < 3; ++ky) {
            const int yy = y + ky - 1;
            if (yy < 0 || yy > 31) continue;
#pragma unroll
            for (int kx = 0; kx < 3; ++kx) {
                const int xx = x + kx - 1;
                if (xx < 0 || xx > 31) continue;
                pe += wk[ky * 3 + kx] * vm[yy * WW + xx];
            }
        }
        att[((size_t)b * 128 + h * 16 + d) * HW + i] = o + pe;
    }
}

// ---------------------------------------------------------------------------
extern "C" void kernel_launch(void* const* d_in, const int* in_sizes, int n_in,
                              void* d_out, int out_size, void* d_ws, size_t ws_size,
                              hipStream_t stream)
{
    const float* x      = (const float*)d_in[0];
    const float* cv1_w  = (const float*)d_in[1];
    const float* bn1_g  = (const float*)d_in[2];
    const float* bn1_b  = (const float*)d_in[3];
    const float* qkv_w  = (const float*)d_in[4];
    const float* pe_w   = (const float*)d_in[5];
    const float* proj_w = (const float*)d_in[6];
    const float* ffn1_w = (const float*)d_in[7];
    const float* fbn1_g = (const float*)d_in[8];
    const float* fbn1_b = (const float*)d_in[9];
    const float* ffn2_w = (const float*)d_in[10];
    const float* fbn2_g = (const float*)d_in[11];
    const float* fbn2_b = (const float*)d_in[12];
    const float* cv2_w  = (const float*)d_in[13];
    const float* bn2_g  = (const float*)d_in[14];
    const float* bn2_b  = (const float*)d_in[15];
    float* out = (float*)d_out;

    const int B = 8;
    float* ws = (float*)d_ws;
    // FIXED layout (floats), no ws_size branching. Peak = 8,650,752 fl = 34.6MB
    // (below the 38.8MB watermark proven in rounds 1-2):
    //   y    @ 0          2,097,152  (live until cv2)
    //   qkv  @ 2,097,152  3,145,728  (dead after merge)
    //   part @ 5,242,880  2,359,296  (64*2*18*1024; dead after merge)
    //   att  @ 7,602,176  1,048,576  (dead after proj)
    //   a2   @ 2,097,152  (reuse qkv[0:1M), after merge)
    //   f1   @ 3,145,728  (reuse qkv[1M:3M))
    //   f2   @ 5,242,880  (reuse part)
    float* y    = ws;
    float* qkv  = ws + 2097152;
    float* part = ws + 5242880;
    float* att  = ws + 7602176;
    float* a2   = ws + 2097152;
    float* f1   = ws + 3145728;
    float* f2   = ws + 5242880;

    dim3 blk(256);

    // 1) cv1: x(256) -> y(256), BN+ReLU
    conv1x1_kernel<256, 0><<<dim3(2, 32, B), blk, 0, stream>>>(
        x, 256, 0, nullptr, 0, 0, cv1_w, bn1_g, bn1_b, y, 256, 1);

    // 2) qkv: y[:,0:128] -> qkv(384)
    conv1x1_kernel<128, 0><<<dim3(2, 48, B), blk, 0, stream>>>(
        y, 256, 0, nullptr, 0, 0, qkv_w, nullptr, nullptr, qkv, 384, 0);

    // 3) attention partials (fixed Jc=2)
    attn_part_kernel<<<dim3(2, 2, 64), blk, 0, stream>>>(qkv, part, 512);

    // 4) merge + PE
    attn_merge_kernel<<<dim3(4, 8, B), blk, 0, stream>>>(part, qkv, pe_w, att);

    // 5) proj: att(128) -> a2(128)
    conv1x1_kernel<128, 0><<<dim3(2, 16, B), blk, 0, stream>>>(
        att, 128, 0, nullptr, 0, 0, proj_w, nullptr, nullptr, a2, 128, 0);

    // 6) ffn1: a2(128) -> f1(256), BN+ReLU
    conv1x1_kernel<128, 0><<<dim3(2, 32, B), blk, 0, stream>>>(
        a2, 128, 0, nullptr, 0, 0, ffn1_w, fbn1_g, fbn1_b, f1, 256, 1);

    // 7) ffn2: f1(256) -> f2(128), BN
    conv1x1_kernel<256, 0><<<dim3(2, 16, B), blk, 0, stream>>>(
        f1, 256, 0, nullptr, 0, 0, ffn2_w, fbn2_g, fbn2_b, f2, 128, 0);

    // 8) cv2: concat(f2, y[:,128:256]) -> out(256), BN+ReLU
    conv1x1_kernel<128, 128><<<dim3(2, 32, B), blk, 0, stream>>>(
        f2, 128, 0, y, 256, 128, cv2_w, bn2_g, bn2_b, out, 256, 1);
}

// Round 6
// 391.532 us; speedup vs baseline: 1.3281x; 1.0906x over previous
//
#include <hip/hip_runtime.h>

#define HW 1024
#define WW 32

typedef _Float16 f16x8 __attribute__((ext_vector_type(8)));
typedef _Float16 f16x4 __attribute__((ext_vector_type(4)));
typedef float    f32x4 __attribute__((ext_vector_type(4)));

// ---------------------------------------------------------------------------
// Weight split pre-pass: all six fp32 weight mats -> fp16 hi/lo planes.
// grid 1024 x 256. Segment boundaries in units of 256-element blocks.
// half offsets: cv1 0 | qkv 65536 | proj 114688 | ffn1 131072 | ffn2 163840 | cv2 196608
// ---------------------------------------------------------------------------
__global__ __launch_bounds__(256) void wsplit_kernel(
    const float* __restrict__ w0, const float* __restrict__ w1,
    const float* __restrict__ w2, const float* __restrict__ w3,
    const float* __restrict__ w4, const float* __restrict__ w5,
    _Float16* __restrict__ wh, _Float16* __restrict__ wl)
{
    const int bid = blockIdx.x, t = threadIdx.x;
    const float* src; size_t off; int idx;
    if      (bid < 256) { src = w0; off = 0;      idx = bid * 256 + t; }
    else if (bid < 448) { src = w1; off = 65536;  idx = (bid - 256) * 256 + t; }
    else if (bid < 512) { src = w2; off = 114688; idx = (bid - 448) * 256 + t; }
    else if (bid < 640) { src = w3; off = 131072; idx = (bid - 512) * 256 + t; }
    else if (bid < 768) { src = w4; off = 163840; idx = (bid - 640) * 256 + t; }
    else                { src = w5; off = 196608; idx = (bid - 768) * 256 + t; }
    const float v = src[idx];
    const _Float16 h = (_Float16)v;
    wh[off + idx] = h;
    wl[off + idx] = (_Float16)(v - (float)h);
}

// ---------------------------------------------------------------------------
// x (B,256,HW) fp32 NCHW -> NHWC fp16 hi/lo planes (B*HW, 256).
// LDS 64x64 tile transpose. grid (16, 4, 8), block 256.
// ---------------------------------------------------------------------------
__global__ __launch_bounds__(256) void xsplit_kernel(
    const float* __restrict__ x, _Float16* __restrict__ xh, _Float16* __restrict__ xl)
{
    __shared__ float t[64][65];
    const int b = blockIdx.z, c0 = blockIdx.y * 64, n0 = blockIdx.x * 64;
    const int tid = threadIdx.x;
    {
        const int c = tid >> 2, q = tid & 3;
        const float* src = x + ((size_t)b * 256 + c0 + c) * HW + n0;
#pragma unroll
        for (int s = 0; s < 4; ++s) {
            float4 v = *(const float4*)(src + q * 16 + s * 4);
            t[c][q * 16 + s * 4 + 0] = v.x; t[c][q * 16 + s * 4 + 1] = v.y;
            t[c][q * 16 + s * 4 + 2] = v.z; t[c][q * 16 + s * 4 + 3] = v.w;
        }
    }
    __syncthreads();
    {
        const int n = tid >> 2, cq = tid & 3;
        f16x8 h0, h1, l0, l1;
#pragma unroll
        for (int j = 0; j < 8; ++j) {
            float v0 = t[cq * 16 + j][n], v1 = t[cq * 16 + 8 + j][n];
            _Float16 a = (_Float16)v0, c = (_Float16)v1;
            h0[j] = a; l0[j] = (_Float16)(v0 - (float)a);
            h1[j] = c; l1[j] = (_Float16)(v1 - (float)c);
        }
        const size_t o = ((size_t)b * HW + n0 + n) * 256 + c0 + cq * 16;
        *(f16x8*)(xh + o) = h0; *(f16x8*)(xh + o + 8) = h1;
        *(f16x8*)(xl + o) = l0; *(f16x8*)(xl + o + 8) = l1;
    }
}

// ---------------------------------------------------------------------------
// MFMA 1x1 conv: out[co,n] = sum_ci W[co,ci] * ACT[n,ci], fp16 2-term split,
// 3x mfma_f32_16x16x32_f16 per K-step. Activations NHWC fp16 hi/lo planes.
// Optional concat: ci < SPLIT from src1, else src2 (stride/coff per source).
// MODE: bit0=BN, bit1=ReLU, bit2=fp32 NCHW output (else fp16-pair NHWC).
// block 256 = 4 waves; wave = 16 co x 64 n. grid (8192/64, cout/64).
// ---------------------------------------------------------------------------
template<int CIN, int SPLIT, int MODE>
__global__ __launch_bounds__(256) void conv_mfma_kernel(
    const _Float16* __restrict__ s1h, const _Float16* __restrict__ s1l, int str1, int coff1,
    const _Float16* __restrict__ s2h, const _Float16* __restrict__ s2l, int str2, int coff2,
    const _Float16* __restrict__ wh, const _Float16* __restrict__ wl,
    const float* __restrict__ g, const float* __restrict__ bbv,
    _Float16* __restrict__ oh, _Float16* __restrict__ ol,
    float* __restrict__ of, int cout)
{
    const int wv = threadIdx.x >> 6, lane = threadIdx.x & 63;
    const int lr = lane & 15, lg = lane >> 4;
    const int n0 = blockIdx.x * 64;
    const int co0 = blockIdx.y * 64 + wv * 16;
    constexpr int KS = CIN / 32;

    f16x8 Ah[KS], Al[KS];
    const _Float16* wrh = wh + (size_t)(co0 + lr) * CIN + lg * 8;
    const _Float16* wrl = wl + (size_t)(co0 + lr) * CIN + lg * 8;
#pragma unroll
    for (int k = 0; k < KS; ++k) {
        Ah[k] = *(const f16x8*)(wrh + k * 32);
        Al[k] = *(const f16x8*)(wrl + k * 32);
    }

#pragma unroll
    for (int t = 0; t < 4; ++t) {
        const int n = n0 + t * 16 + lr;
        f32x4 acc = {0.f, 0.f, 0.f, 0.f};
#pragma unroll
        for (int k = 0; k < KS; ++k) {
            const int ci = k * 32 + lg * 8;
            const _Float16 *bhp, *blp;
            if (k * 32 < SPLIT) {
                bhp = s1h + (size_t)n * str1 + coff1 + ci;
                blp = s1l + (size_t)n * str1 + coff1 + ci;
            } else {
                bhp = s2h + (size_t)n * str2 + coff2 + (ci - SPLIT);
                blp = s2l + (size_t)n * str2 + coff2 + (ci - SPLIT);
            }
            f16x8 Bh = *(const f16x8*)bhp;
            f16x8 Bl = *(const f16x8*)blp;
            acc = __builtin_amdgcn_mfma_f32_16x16x32_f16(Ah[k], Bh, acc, 0, 0, 0);
            acc = __builtin_amdgcn_mfma_f32_16x16x32_f16(Ah[k], Bl, acc, 0, 0, 0);
            acc = __builtin_amdgcn_mfma_f32_16x16x32_f16(Al[k], Bh, acc, 0, 0, 0);
        }
        // D: col(n) = lane&15 = lr, row(co) = (lane>>4)*4 + r  [guide-verified]
        const int cob = co0 + lg * 4;
        float v[4];
#pragma unroll
        for (int r = 0; r < 4; ++r) {
            float t2 = acc[r];
            if constexpr (MODE & 1) t2 = t2 * g[cob + r] + bbv[cob + r];
            if constexpr (MODE & 2) t2 = fmaxf(t2, 0.f);
            v[r] = t2;
        }
        if constexpr (MODE & 4) {
            const int b = n >> 10, p = n & 1023;
#pragma unroll
            for (int r = 0; r < 4; ++r)
                of[((size_t)b * cout + cob + r) * HW + p] = v[r];
        } else {
            f16x4 hv, lv;
#pragma unroll
            for (int r = 0; r < 4; ++r) {
                _Float16 hh = (_Float16)v[r];
                hv[r] = hh; lv[r] = (_Float16)(v[r] - (float)hh);
            }
            *(f16x4*)(oh + (size_t)n * cout + cob) = hv;
            *(f16x4*)(ol + (size_t)n * cout + cob) = lv;
        }
    }
}

// ---------------------------------------------------------------------------
// Attention partials (round-5 proven math; part stored fp16 + fp32 m/l).
// grid (2,2,64), block 256. part chunk per (bh,jc): 10240 floats
//   [0,8192): 16x1024 fp16 acc rows | [8192,9216): m fp32 | [9216,10240): l fp32
// ---------------------------------------------------------------------------
__global__ __launch_bounds__(256) void attn_part_kernel(
    const float* __restrict__ qkv, float* __restrict__ part, int jlen)
{
    const int bh = blockIdx.z;
    const int jc = blockIdx.y;
    const int i0 = blockIdx.x * 512 + threadIdx.x;
    const int i1 = i0 + 256;
    const float scale = 0.25f;

    const float* base = qkv + (size_t)bh * 48 * HW;

    float q0[16], q1[16];
#pragma unroll
    for (int d = 0; d < 16; ++d) {
        q0[d] = base[(size_t)d * HW + i0] * scale;
        q1[d] = base[(size_t)d * HW + i1] * scale;
    }

    float m0 = -1e30f, l0 = 0.f, m1 = -1e30f, l1 = 0.f;
    float acc0[16], acc1[16];
#pragma unroll
    for (int d = 0; d < 16; ++d) { acc0[d] = 0.f; acc1[d] = 0.f; }

    const int j0 = jc * jlen;
    for (int jj = j0; jj < j0 + jlen; jj += 4) {
        float4 kf[16];
#pragma unroll
        for (int d = 0; d < 16; ++d)
            kf[d] = *(const float4*)(base + (size_t)(16 + d) * HW + jj);

        float s00 = 0.f, s01 = 0.f, s02 = 0.f, s03 = 0.f;
        float s10 = 0.f, s11 = 0.f, s12 = 0.f, s13 = 0.f;
#pragma unroll
        for (int d = 0; d < 16; ++d) {
            s00 += q0[d] * kf[d].x; s01 += q0[d] * kf[d].y;
            s02 += q0[d] * kf[d].z; s03 += q0[d] * kf[d].w;
            s10 += q1[d] * kf[d].x; s11 += q1[d] * kf[d].y;
            s12 += q1[d] * kf[d].z; s13 += q1[d] * kf[d].w;
        }

        float4 vf[16];
#pragma unroll
        for (int d = 0; d < 16; ++d)
            vf[d] = *(const float4*)(base + (size_t)(32 + d) * HW + jj);

        float m4 = fmaxf(fmaxf(s00, s01), fmaxf(s02, s03));
        float mn = fmaxf(m0, m4);
        float p0 = __expf(s00 - mn), p1 = __expf(s01 - mn);
        float p2 = __expf(s02 - mn), p3 = __expf(s03 - mn);
        if (mn > m0) {
            const float c = __expf(m0 - mn);
            l0 *= c;
#pragma unroll
            for (int d = 0; d < 16; ++d) acc0[d] *= c;
            m0 = mn;
        }
        l0 += (p0 + p1) + (p2 + p3);
        float n4 = fmaxf(fmaxf(s10, s11), fmaxf(s12, s13));
        float nn = fmaxf(m1, n4);
        float r0 = __expf(s10 - nn), r1 = __expf(s11 - nn);
        float r2 = __expf(s12 - nn), r3 = __expf(s13 - nn);
        if (nn > m1) {
            const float c = __expf(m1 - nn);
            l1 *= c;
#pragma unroll
            for (int d = 0; d < 16; ++d) acc1[d] *= c;
            m1 = nn;
        }
        l1 += (r0 + r1) + (r2 + r3);

#pragma unroll
        for (int d = 0; d < 16; ++d) {
            acc0[d] += p0 * vf[d].x + p1 * vf[d].y + p2 * vf[d].z + p3 * vf[d].w;
            acc1[d] += r0 * vf[d].x + r1 * vf[d].y + r2 * vf[d].z + r3 * vf[d].w;
        }
    }

    float* chunk = part + (size_t)(bh * 2 + jc) * 10240;
    _Float16* ph = (_Float16*)chunk;
#pragma unroll
    for (int d = 0; d < 16; ++d) {
        ph[(size_t)d * 1024 + i0] = (_Float16)acc0[d];
        ph[(size_t)d * 1024 + i1] = (_Float16)acc1[d];
    }
    chunk[8192 + i0] = m0; chunk[9216 + i0] = l0;
    chunk[8192 + i1] = m1; chunk[9216 + i1] = l1;
}

// ---------------------------------------------------------------------------
// Merge 2 partials + depthwise-3x3 PE; output NHWC fp16 hi/lo (B*HW, 128).
// grid (4, 8, 8), block 256.
// ---------------------------------------------------------------------------
__global__ __launch_bounds__(256) void attn_merge_kernel(
    const float* __restrict__ part, const float* __restrict__ qkv,
    const float* __restrict__ pe_w, _Float16* __restrict__ atth,
    _Float16* __restrict__ attl)
{
    const int i = blockIdx.x * 256 + threadIdx.x;
    const int h = blockIdx.y, b = blockIdx.z;
    const int bh = b * 8 + h;

    const float* c0 = part + (size_t)bh * 2 * 10240;
    const float* c1 = c0 + 10240;
    const _Float16* p0h = (const _Float16*)c0;
    const _Float16* p1h = (const _Float16*)c1;
    const float m0 = c0[8192 + i], l0 = c0[9216 + i];
    const float m1 = c1[8192 + i], l1 = c1[9216 + i];
    const float M  = fmaxf(m0, m1);
    const float s0 = __expf(m0 - M), s1 = __expf(m1 - M);
    const float inv = 1.f / (l0 * s0 + l1 * s1);

    const float* vbase = qkv + ((size_t)bh * 48 + 32) * HW;
    const int y = i >> 5, x = i & 31;

    float o16[16];
#pragma unroll
    for (int d = 0; d < 16; ++d) {
        float o = ((float)p0h[(size_t)d * 1024 + i] * s0 +
                   (float)p1h[(size_t)d * 1024 + i] * s1) * inv;
        const float* vm = vbase + (size_t)d * HW;
        const float* wk = pe_w + (size_t)(h * 16 + d) * 9;
        float pe = 0.f;
#pragma unroll
        for (int ky = 0; ky < 3; ++ky) {
            const int yy = y + ky - 1;
            if (yy < 0 || yy > 31) continue;
#pragma unroll
            for (int kx = 0; kx < 3; ++kx) {
                const int xx = x + kx - 1;
                if (xx < 0 || xx > 31) continue;
                pe += wk[ky * 3 + kx] * vm[yy * WW + xx];
            }
        }
        o16[d] = o + pe;
    }

    f16x8 h0, h1, l0v, l1v;
#pragma unroll
    for (int j = 0; j < 8; ++j) {
        _Float16 a = (_Float16)o16[j],     c = (_Float16)o16[8 + j];
        h0[j] = a; l0v[j] = (_Float16)(o16[j] - (float)a);
        h1[j] = c; l1v[j] = (_Float16)(o16[8 + j] - (float)c);
    }
    const size_t o = ((size_t)b * HW + i) * 128 + h * 16;
    *(f16x8*)(atth + o) = h0; *(f16x8*)(atth + o + 8) = h1;
    *(f16x8*)(attl + o) = l0v; *(f16x8*)(attl + o + 8) = l1v;
}

// ---------------------------------------------------------------------------
extern "C" void kernel_launch(void* const* d_in, const int* in_sizes, int n_in,
                              void* d_out, int out_size, void* d_ws, size_t ws_size,
                              hipStream_t stream)
{
    const float* x      = (const float*)d_in[0];
    const float* cv1_w  = (const float*)d_in[1];
    const float* bn1_g  = (const float*)d_in[2];
    const float* bn1_b  = (const float*)d_in[3];
    const float* qkv_w  = (const float*)d_in[4];
    const float* pe_w   = (const float*)d_in[5];
    const float* proj_w = (const float*)d_in[6];
    const float* ffn1_w = (const float*)d_in[7];
    const float* fbn1_g = (const float*)d_in[8];
    const float* fbn1_b = (const float*)d_in[9];
    const float* ffn2_w = (const float*)d_in[10];
    const float* fbn2_g = (const float*)d_in[11];
    const float* fbn2_b = (const float*)d_in[12];
    const float* cv2_w  = (const float*)d_in[13];
    const float* bn2_g  = (const float*)d_in[14];
    const float* bn2_b  = (const float*)d_in[15];
    float* out = (float*)d_out;

    float* ws = (float*)d_ws;
    // Fixed layout (float units). Peak = 8,912,896 fl = 35.65 MB (< 38.8 proven).
    //   wbuf @ 0          262,144   (fp16 hi/lo weight planes; live always)
    //   xt   @ 262,144    2,097,152 (x NHWC fp16^2; dead after cv1)
    //   y    @ 2,359,296  2,097,152 (cv1 out NHWC fp16^2; live until cv2)
    //   qkv  @ 4,456,448  3,145,728 (fp32 NCHW; dead after merge)
    //   part @ 7,602,176  1,310,720 (fp16 acc + fp32 m/l; dead after merge)
    //   att  @ 262,144    1,048,576 (reuse xt; NHWC fp16^2; dead after proj)
    //   a2   @ 1,310,720  1,048,576 (reuse xt tail; dead after ffn1)
    //   f1   @ 4,456,448  2,097,152 (reuse qkv; dead after ffn2)
    //   f2   @ 6,553,600  1,048,576
    _Float16* wh   = (_Float16*)ws;
    _Float16* wl   = wh + 262144;
    _Float16* xh   = (_Float16*)(ws + 262144);
    _Float16* xl   = xh + 2097152;
    _Float16* yh   = (_Float16*)(ws + 2359296);
    _Float16* yl   = yh + 2097152;
    float*    qkv  = ws + 4456448;
    float*    part = ws + 7602176;
    _Float16* atth = (_Float16*)(ws + 262144);
    _Float16* attl = atth + 1048576;
    _Float16* a2h  = (_Float16*)(ws + 1310720);
    _Float16* a2l  = a2h + 1048576;
    _Float16* f1h  = (_Float16*)(ws + 4456448);
    _Float16* f1l  = f1h + 2097152;
    _Float16* f2h  = (_Float16*)(ws + 6553600);
    _Float16* f2l  = f2h + 1048576;

    dim3 blk(256);

    // 0a) weight fp16 split
    wsplit_kernel<<<dim3(1024), blk, 0, stream>>>(
        cv1_w, qkv_w, proj_w, ffn1_w, ffn2_w, cv2_w, wh, wl);
    // 0b) x -> NHWC fp16^2
    xsplit_kernel<<<dim3(16, 4, 8), blk, 0, stream>>>(x, xh, xl);

    // 1) cv1: xt(256) -> y(256) NHWC fp16^2, BN+ReLU           MODE=3
    conv_mfma_kernel<256, 256, 3><<<dim3(128, 4), blk, 0, stream>>>(
        xh, xl, 256, 0, nullptr, nullptr, 0, 0,
        wh + 0, wl + 0, bn1_g, bn1_b, yh, yl, nullptr, 256);

    // 2) qkv: y[:,:128] -> qkv(384) fp32 NCHW                  MODE=4
    conv_mfma_kernel<128, 128, 4><<<dim3(128, 6), blk, 0, stream>>>(
        yh, yl, 256, 0, nullptr, nullptr, 0, 0,
        wh + 65536, wl + 65536, nullptr, nullptr, nullptr, nullptr, qkv, 384);

    // 3) attention partials (round-5 proven; fp16 part)
    attn_part_kernel<<<dim3(2, 2, 64), blk, 0, stream>>>(qkv, part, 512);

    // 4) merge + PE -> att NHWC fp16^2
    attn_merge_kernel<<<dim3(4, 8, 8), blk, 0, stream>>>(part, qkv, pe_w, atth, attl);

    // 5) proj: att(128) -> a2(128) NHWC fp16^2                 MODE=0
    conv_mfma_kernel<128, 128, 0><<<dim3(128, 2), blk, 0, stream>>>(
        atth, attl, 128, 0, nullptr, nullptr, 0, 0,
        wh + 114688, wl + 114688, nullptr, nullptr, a2h, a2l, nullptr, 128);

    // 6) ffn1: a2(128) -> f1(256), BN+ReLU                     MODE=3
    conv_mfma_kernel<128, 128, 3><<<dim3(128, 4), blk, 0, stream>>>(
        a2h, a2l, 128, 0, nullptr, nullptr, 0, 0,
        wh + 131072, wl + 131072, fbn1_g, fbn1_b, f1h, f1l, nullptr, 256);

    // 7) ffn2: f1(256) -> f2(128), BN                          MODE=1
    conv_mfma_kernel<256, 256, 1><<<dim3(128, 2), blk, 0, stream>>>(
        f1h, f1l, 256, 0, nullptr, nullptr, 0, 0,
        wh + 163840, wl + 163840, fbn2_g, fbn2_b, f2h, f2l, nullptr, 128);

    // 8) cv2: concat(f2(128), y[:,128:256]) -> out fp32 NCHW, BN+ReLU  MODE=7
    conv_mfma_kernel<256, 128, 7><<<dim3(128, 4), blk, 0, stream>>>(
        f2h, f2l, 128, 0, yh, yl, 256, 128,
        wh + 196608, wl + 196608, bn2_g, bn2_b, nullptr, nullptr, out, 256);
}

// Round 11
// 244.266 us; speedup vs baseline: 2.1288x; 1.6029x over previous
//
#include <hip/hip_runtime.h>

#define HW 1024
#define WW 32

typedef _Float16 f16x8 __attribute__((ext_vector_type(8)));
typedef _Float16 f16x4 __attribute__((ext_vector_type(4)));
typedef float    f32x4 __attribute__((ext_vector_type(4)));

// ---------------------------------------------------------------------------
// Weight split pre-pass: all six fp32 weight mats -> fp16 hi/lo planes.
// ---------------------------------------------------------------------------
__global__ __launch_bounds__(256) void wsplit_kernel(
    const float* __restrict__ w0, const float* __restrict__ w1,
    const float* __restrict__ w2, const float* __restrict__ w3,
    const float* __restrict__ w4, const float* __restrict__ w5,
    _Float16* __restrict__ wh, _Float16* __restrict__ wl)
{
    const int bid = blockIdx.x, t = threadIdx.x;
    const float* src; size_t off; int idx;
    if      (bid < 256) { src = w0; off = 0;      idx = bid * 256 + t; }
    else if (bid < 448) { src = w1; off = 65536;  idx = (bid - 256) * 256 + t; }
    else if (bid < 512) { src = w2; off = 114688; idx = (bid - 448) * 256 + t; }
    else if (bid < 640) { src = w3; off = 131072; idx = (bid - 512) * 256 + t; }
    else if (bid < 768) { src = w4; off = 163840; idx = (bid - 640) * 256 + t; }
    else                { src = w5; off = 196608; idx = (bid - 768) * 256 + t; }
    const float v = src[idx];
    const _Float16 h = (_Float16)v;
    wh[off + idx] = h;
    wl[off + idx] = (_Float16)(v - (float)h);
}

// ---------------------------------------------------------------------------
// x (B,256,HW) fp32 NCHW -> NHWC fp16 hi/lo planes (B*HW, 256).
// ---------------------------------------------------------------------------
__global__ __launch_bounds__(256) void xsplit_kernel(
    const float* __restrict__ x, _Float16* __restrict__ xh, _Float16* __restrict__ xl)
{
    __shared__ float t[64][65];
    const int b = blockIdx.z, c0 = blockIdx.y * 64, n0 = blockIdx.x * 64;
    const int tid = threadIdx.x;
    {
        const int c = tid >> 2, q = tid & 3;
        const float* src = x + ((size_t)b * 256 + c0 + c) * HW + n0;
#pragma unroll
        for (int s = 0; s < 4; ++s) {
            float4 v = *(const float4*)(src + q * 16 + s * 4);
            t[c][q * 16 + s * 4 + 0] = v.x; t[c][q * 16 + s * 4 + 1] = v.y;
            t[c][q * 16 + s * 4 + 2] = v.z; t[c][q * 16 + s * 4 + 3] = v.w;
        }
    }
    __syncthreads();
    {
        const int n = tid >> 2, cq = tid & 3;
        f16x8 h0, h1, l0, l1;
#pragma unroll
        for (int j = 0; j < 8; ++j) {
            float v0 = t[cq * 16 + j][n], v1 = t[cq * 16 + 8 + j][n];
            _Float16 a = (_Float16)v0, c = (_Float16)v1;
            h0[j] = a; l0[j] = (_Float16)(v0 - (float)a);
            h1[j] = c; l1[j] = (_Float16)(v1 - (float)c);
        }
        const size_t o = ((size_t)b * HW + n0 + n) * 256 + c0 + cq * 16;
        *(f16x8*)(xh + o) = h0; *(f16x8*)(xh + o + 8) = h1;
        *(f16x8*)(xl + o) = l0; *(f16x8*)(xl + o + 8) = l1;
    }
}

// ---------------------------------------------------------------------------
// MFMA 1x1 conv (validated round 6). NHWC fp16 hi/lo activations.
// MODE: bit0=BN, bit1=ReLU, bit2=fp32 NCHW output (else fp16-pair NHWC).
// ---------------------------------------------------------------------------
template<int CIN, int SPLIT, int MODE>
__global__ __launch_bounds__(256) void conv_mfma_kernel(
    const _Float16* __restrict__ s1h, const _Float16* __restrict__ s1l, int str1, int coff1,
    const _Float16* __restrict__ s2h, const _Float16* __restrict__ s2l, int str2, int coff2,
    const _Float16* __restrict__ wh, const _Float16* __restrict__ wl,
    const float* __restrict__ g, const float* __restrict__ bbv,
    _Float16* __restrict__ oh, _Float16* __restrict__ ol,
    float* __restrict__ of, int cout)
{
    const int wv = threadIdx.x >> 6, lane = threadIdx.x & 63;
    const int lr = lane & 15, lg = lane >> 4;
    const int n0 = blockIdx.x * 64;
    const int co0 = blockIdx.y * 64 + wv * 16;
    constexpr int KS = CIN / 32;

    f16x8 Ah[KS], Al[KS];
    const _Float16* wrh = wh + (size_t)(co0 + lr) * CIN + lg * 8;
    const _Float16* wrl = wl + (size_t)(co0 + lr) * CIN + lg * 8;
#pragma unroll
    for (int k = 0; k < KS; ++k) {
        Ah[k] = *(const f16x8*)(wrh + k * 32);
        Al[k] = *(const f16x8*)(wrl + k * 32);
    }

#pragma unroll
    for (int t = 0; t < 4; ++t) {
        const int n = n0 + t * 16 + lr;
        f32x4 acc = {0.f, 0.f, 0.f, 0.f};
#pragma unroll
        for (int k = 0; k < KS; ++k) {
            const int ci = k * 32 + lg * 8;
            const _Float16 *bhp, *blp;
            if (k * 32 < SPLIT) {
                bhp = s1h + (size_t)n * str1 + coff1 + ci;
                blp = s1l + (size_t)n * str1 + coff1 + ci;
            } else {
                bhp = s2h + (size_t)n * str2 + coff2 + (ci - SPLIT);
                blp = s2l + (size_t)n * str2 + coff2 + (ci - SPLIT);
            }
            f16x8 Bh = *(const f16x8*)bhp;
            f16x8 Bl = *(const f16x8*)blp;
            acc = __builtin_amdgcn_mfma_f32_16x16x32_f16(Ah[k], Bh, acc, 0, 0, 0);
            acc = __builtin_amdgcn_mfma_f32_16x16x32_f16(Ah[k], Bl, acc, 0, 0, 0);
            acc = __builtin_amdgcn_mfma_f32_16x16x32_f16(Al[k], Bh, acc, 0, 0, 0);
        }
        const int cob = co0 + lg * 4;
        float v[4];
#pragma unroll
        for (int r = 0; r < 4; ++r) {
            float t2 = acc[r];
            if constexpr (MODE & 1) t2 = t2 * g[cob + r] + bbv[cob + r];
            if constexpr (MODE & 2) t2 = fmaxf(t2, 0.f);
            v[r] = t2;
        }
        if constexpr (MODE & 4) {
            const int b = n >> 10, p = n & 1023;
#pragma unroll
            for (int r = 0; r < 4; ++r)
                of[((size_t)b * cout + cob + r) * HW + p] = v[r];
        } else {
            f16x4 hv, lv;
#pragma unroll
            for (int r = 0; r < 4; ++r) {
                _Float16 hh = (_Float16)v[r];
                hv[r] = hh; lv[r] = (_Float16)(v[r] - (float)hh);
            }
            *(f16x4*)(oh + (size_t)n * cout + cob) = hv;
            *(f16x4*)(ol + (size_t)n * cout + cob) = lv;
        }
    }
}

// ---------------------------------------------------------------------------
// MFMA flash attention. Per block: one (b,h), 64 queries (4 waves x 16).
// S^T = K^T*Q via 3x mfma_16x16x16_f16 (hi/lo split); softmax per-lane-column
// (i = lane&15), 2 shfl_xor; O^T = V^T*P^T (P frag = S frag layout, no
// shuffles). K/V staged per 256-key chunk in LDS (khiT/kloT [256][18] pad ->
// bank-free b64 reads; vS [16][264]).
// Output: normalized O, NHWC fp16 hi/lo (B*HW, 128). grid (16, 64), block 256.
// ---------------------------------------------------------------------------
__global__ __launch_bounds__(256) void attn_mfma_kernel(
    const float* __restrict__ qkv,
    _Float16* __restrict__ atth, _Float16* __restrict__ attl)
{
    __shared__ _Float16 khiT[256 * 18];
    __shared__ _Float16 kloT[256 * 18];
    __shared__ _Float16 vS[16 * 264];

    const int bh = blockIdx.y;
    const int b = bh >> 3, h = bh & 7;
    const int i0 = blockIdx.x * 64 + (threadIdx.x >> 6) * 16;
    const int lane = threadIdx.x & 63;
    const int li = lane & 15, lg = lane >> 4;

    const float* base = qkv + (size_t)bh * 48 * HW;

    // Q B-frag (col i = li, k = d = lg*4+e), scale folded before split
    f16x4 Qh, Ql;
    {
        const int iq = i0 + li;
#pragma unroll
        for (int e = 0; e < 4; ++e) {
            float qv = base[(size_t)(lg * 4 + e) * HW + iq] * 0.25f;
            _Float16 hh = (_Float16)qv;
            Qh[e] = hh; Ql[e] = (_Float16)(qv - (float)hh);
        }
    }

    f32x4 O = {0.f, 0.f, 0.f, 0.f};
    float m = -3e38f, l = 0.f;

    const int td = threadIdx.x >> 4;   // staging: d row 0..15
    const int tj = threadIdx.x & 15;   // staging: j lane

    for (int c = 0; c < 4; ++c) {
        __syncthreads();
        const float* krow = base + (size_t)(16 + td) * HW + c * 256;
        const float* vrow = base + (size_t)(32 + td) * HW + c * 256;
#pragma unroll
        for (int s = 0; s < 16; ++s) {
            const int j = tj + s * 16;
            const float kv = krow[j];
            const _Float16 kh = (_Float16)kv;
            khiT[j * 18 + td] = kh;
            kloT[j * 18 + td] = (_Float16)(kv - (float)kh);
            vS[td * 264 + j] = (_Float16)vrow[j];
        }
        __syncthreads();

        for (int jt = 0; jt < 16; ++jt) {
            const int jrow = jt * 16 + li;
            f16x4 Kh = *(const f16x4*)&khiT[jrow * 18 + lg * 4];
            f16x4 Kl = *(const f16x4*)&kloT[jrow * 18 + lg * 4];
            f16x4 Vh = *(const f16x4*)&vS[li * 264 + jt * 16 + lg * 4];

            f32x4 S = {0.f, 0.f, 0.f, 0.f};
            S = __builtin_amdgcn_mfma_f32_16x16x16f16(Kh, Qh, S, 0, 0, 0);
            S = __builtin_amdgcn_mfma_f32_16x16x16f16(Kh, Ql, S, 0, 0, 0);
            S = __builtin_amdgcn_mfma_f32_16x16x16f16(Kl, Qh, S, 0, 0, 0);

            float m4 = fmaxf(fmaxf(S[0], S[1]), fmaxf(S[2], S[3]));
            m4 = fmaxf(m4, __shfl_xor(m4, 16));
            m4 = fmaxf(m4, __shfl_xor(m4, 32));
            const float mn = fmaxf(m, m4);
            const float p0 = __expf(S[0] - mn), p1 = __expf(S[1] - mn);
            const float p2 = __expf(S[2] - mn), p3 = __expf(S[3] - mn);
            const float cs = __expf(m - mn);
            m = mn;
            float ts = (p0 + p1) + (p2 + p3);
            ts += __shfl_xor(ts, 16);
            ts += __shfl_xor(ts, 32);
            l = l * cs + ts;
            O[0] *= cs; O[1] *= cs; O[2] *= cs; O[3] *= cs;
            f16x4 P;
            P[0] = (_Float16)p0; P[1] = (_Float16)p1;
            P[2] = (_Float16)p2; P[3] = (_Float16)p3;
            O = __builtin_amdgcn_mfma_f32_16x16x16f16(Vh, P, O, 0, 0, 0);
        }
    }

    const float inv = 1.f / l;
    const int iq = i0 + li;
    f16x4 oh, ol;
#pragma unroll
    for (int r = 0; r < 4; ++r) {
        const float val = O[r] * inv;
        const _Float16 hh = (_Float16)val;
        oh[r] = hh; ol[r] = (_Float16)(val - (float)hh);
    }
    const size_t off = ((size_t)b * HW + iq) * 128 + h * 16 + lg * 4;
    *(f16x4*)(atth + off) = oh;
    *(f16x4*)(attl + off) = ol;
}

// ---------------------------------------------------------------------------
// Depthwise 3x3 PE on v (fp32 NCHW qkv), added into att (fp16-pair NHWC).
// grid (4, 128, 8), block 256.
// ---------------------------------------------------------------------------
__global__ __launch_bounds__(256) void pe_add_kernel(
    const float* __restrict__ qkv, const float* __restrict__ pe_w,
    _Float16* __restrict__ atth, _Float16* __restrict__ attl)
{
    const int p  = blockIdx.x * 256 + threadIdx.x;
    const int ch = blockIdx.y;
    const int b  = blockIdx.z;
    const int hh = ch >> 4, d = ch & 15;

    const float* vmap = qkv + ((size_t)(b * 8 + hh) * 48 + 32 + d) * HW;
    const float* wk = pe_w + ch * 9;
    const int y0 = p >> 5, x0 = p & 31;

    float s = 0.f;
#pragma unroll
    for (int ky = 0; ky < 3; ++ky) {
        const int yy = y0 + ky - 1;
        if (yy < 0 || yy > 31) continue;
#pragma unroll
        for (int kx = 0; kx < 3; ++kx) {
            const int xx = x0 + kx - 1;
            if (xx < 0 || xx > 31) continue;
            s += wk[ky * 3 + kx] * vmap[yy * WW + xx];
        }
    }
    const size_t off = ((size_t)b * HW + p) * 128 + ch;
    const float val = (float)atth[off] + (float)attl[off] + s;
    const _Float16 hv = (_Float16)val;
    atth[off] = hv;
    attl[off] = (_Float16)(val - (float)hv);
}

// ---------------------------------------------------------------------------
extern "C" void kernel_launch(void* const* d_in, const int* in_sizes, int n_in,
                              void* d_out, int out_size, void* d_ws, size_t ws_size,
                              hipStream_t stream)
{
    const float* x      = (const float*)d_in[0];
    const float* cv1_w  = (const float*)d_in[1];
    const float* bn1_g  = (const float*)d_in[2];
    const float* bn1_b  = (const float*)d_in[3];
    const float* qkv_w  = (const float*)d_in[4];
    const float* pe_w   = (const float*)d_in[5];
    const float* proj_w = (const float*)d_in[6];
    const float* ffn1_w = (const float*)d_in[7];
    const float* fbn1_g = (const float*)d_in[8];
    const float* fbn1_b = (const float*)d_in[9];
    const float* ffn2_w = (const float*)d_in[10];
    const float* fbn2_g = (const float*)d_in[11];
    const float* fbn2_b = (const float*)d_in[12];
    const float* cv2_w  = (const float*)d_in[13];
    const float* bn2_g  = (const float*)d_in[14];
    const float* bn2_b  = (const float*)d_in[15];
    float* out = (float*)d_out;

    float* ws = (float*)d_ws;
    // Fixed layout (float units). Peak = 7,602,176 fl = 30.4 MB.
    //   wbuf @ 0          262,144   (fp16 hi/lo weight planes; live always)
    //   xt   @ 262,144    2,097,152 (x NHWC fp16^2; dead after cv1)
    //   y    @ 2,359,296  2,097,152 (cv1 out NHWC fp16^2; live until cv2)
    //   qkv  @ 4,456,448  3,145,728 (fp32 NCHW; dead after pe_add)
    //   att  @ 262,144    1,048,576 (reuse xt; NHWC fp16^2; dead after proj)
    //   a2   @ 1,310,720  1,048,576 (dead after ffn1)
    //   f1   @ 4,456,448  2,097,152 (reuse qkv; dead after ffn2)
    //   f2   @ 6,553,600  1,048,576
    _Float16* wh   = (_Float16*)ws;
    _Float16* wl   = wh + 262144;
    _Float16* xh   = (_Float16*)(ws + 262144);
    _Float16* xl   = xh + 2097152;
    _Float16* yh   = (_Float16*)(ws + 2359296);
    _Float16* yl   = yh + 2097152;
    float*    qkv  = ws + 4456448;
    _Float16* atth = (_Float16*)(ws + 262144);
    _Float16* attl = atth + 1048576;
    _Float16* a2h  = (_Float16*)(ws + 1310720);
    _Float16* a2l  = a2h + 1048576;
    _Float16* f1h  = (_Float16*)(ws + 4456448);
    _Float16* f1l  = f1h + 2097152;
    _Float16* f2h  = (_Float16*)(ws + 6553600);
    _Float16* f2l  = f2h + 1048576;

    dim3 blk(256);

    // 0a) weight fp16 split
    wsplit_kernel<<<dim3(1024), blk, 0, stream>>>(
        cv1_w, qkv_w, proj_w, ffn1_w, ffn2_w, cv2_w, wh, wl);
    // 0b) x -> NHWC fp16^2
    xsplit_kernel<<<dim3(16, 4, 8), blk, 0, stream>>>(x, xh, xl);

    // 1) cv1: xt(256) -> y(256) NHWC fp16^2, BN+ReLU
    conv_mfma_kernel<256, 256, 3><<<dim3(128, 4), blk, 0, stream>>>(
        xh, xl, 256, 0, nullptr, nullptr, 0, 0,
        wh + 0, wl + 0, bn1_g, bn1_b, yh, yl, nullptr, 256);

    // 2) qkv: y[:,:128] -> qkv(384) fp32 NCHW
    conv_mfma_kernel<128, 128, 4><<<dim3(128, 6), blk, 0, stream>>>(
        yh, yl, 256, 0, nullptr, nullptr, 0, 0,
        wh + 65536, wl + 65536, nullptr, nullptr, nullptr, nullptr, qkv, 384);

    // 3) MFMA flash attention -> att NHWC fp16^2 (normalized)
    attn_mfma_kernel<<<dim3(16, 64), blk, 0, stream>>>(qkv, atth, attl);

    // 4) PE depthwise 3x3 added into att
    pe_add_kernel<<<dim3(4, 128, 8), blk, 0, stream>>>(qkv, pe_w, atth, attl);

    // 5) proj: att(128) -> a2(128) NHWC fp16^2
    conv_mfma_kernel<128, 128, 0><<<dim3(128, 2), blk, 0, stream>>>(
        atth, attl, 128, 0, nullptr, nullptr, 0, 0,
        wh + 114688, wl + 114688, nullptr, nullptr, a2h, a2l, nullptr, 128);

    // 6) ffn1: a2(128) -> f1(256), BN+ReLU
    conv_mfma_kernel<128, 128, 3><<<dim3(128, 4), blk, 0, stream>>>(
        a2h, a2l, 128, 0, nullptr, nullptr, 0, 0,
        wh + 131072, wl + 131072, fbn1_g, fbn1_b, f1h, f1l, nullptr, 256);

    // 7) ffn2: f1(256) -> f2(128), BN
    conv_mfma_kernel<256, 256, 1><<<dim3(128, 2), blk, 0, stream>>>(
        f1h, f1l, 256, 0, nullptr, nullptr, 0, 0,
        wh + 163840, wl + 163840, fbn2_g, fbn2_b, f2h, f2l, nullptr, 128);

    // 8) cv2: concat(f2(128), y[:,128:256]) -> out fp32 NCHW, BN+ReLU
    conv_mfma_kernel<256, 128, 7><<<dim3(128, 4), blk, 0, stream>>>(
        f2h, f2l, 128, 0, yh, yl, 256, 128,
        wh + 196608, wl + 196608, bn2_g, bn2_b, nullptr, nullptr, out, 256);
}